// Round 4
// baseline (302.036 us; speedup 1.0000x reference)
//
#include <hip/hip_runtime.h>

typedef __attribute__((ext_vector_type(8)))  short short8;   // 8 bf16 (4 VGPRs)
typedef __attribute__((ext_vector_type(16))) float f32x16;   // 32x32 MFMA acc
typedef unsigned short ushort_t;
typedef unsigned int uint32;

#define NROWS 8192
#define NCODE 8192
#define DIM   512

// ---------------- d_out layout (floats) ----------------
#define OUT_Q      0
#define OUT_LOSS   4194304
#define OUT_IDX    4194305
#define OUT_MIND   4202497
#define OUT_COMMIT 4210689

// ---------------- ws layout (floats) ----------------
#define WS_ENORM  0           // 8192
#define WS_PMIN   8192        // 8192*8
#define WS_PIDX   73728       // 8192*8 ints
#define WS_LPART  147456      // 2048
#define WS_BHI    150528      // 8192*512 bf16
#define WS_BLO    2247680

// ===========================================================================
__device__ inline uint32 bf16_rne(float f) {
    uint32 u = __float_as_uint(f);
    return (u + 0x7FFFu + ((u >> 16) & 1u)) >> 16;
}

// ===========================================================================
// Kernel 1: fused conversion of x and codebook into fragment-ordered bf16
// hi/lo tiles. Tile = 128 rows x 32 k, 8 KB, stored as 8 chunks of 1 KB:
//   chunk c = (r32)*2 + k16 ; within chunk lane L holds 8 bf16:
//   row = r32*32 + (L&31), k = k16*16 + (L>>5)*8 + j
// This IS the mfma_32x32x16 A/B fragment order -> a wave's fragment load is
// one coalesced global_load_dwordx4.
__global__ __launch_bounds__(256) void conv_kernel(const float* __restrict__ x,
                                                   const float* __restrict__ cb,
                                                   ushort_t* __restrict__ ahi,
                                                   ushort_t* __restrict__ alo,
                                                   ushort_t* __restrict__ bhi,
                                                   ushort_t* __restrict__ blo,
                                                   float* __restrict__ enorm) {
    int gid  = blockIdx.x * 256 + threadIdx.x;   // 0..1048575
    bool isA = gid < 524288;
    int g    = isA ? gid : gid - 524288;
    int row  = g >> 6;
    int lane = g & 63;
    int k0   = lane * 8;
    const float* src = (isA ? x : cb) + (size_t)row * DIM + k0;
    float v[8];
    *(float4*)&v[0] = *(const float4*)src;
    *(float4*)&v[4] = *(const float4*)(src + 4);
    float s = 0.0f;
    uint32 h[8], l[8];
    #pragma unroll
    for (int i = 0; i < 8; ++i) {
        s += v[i] * v[i];
        h[i] = bf16_rne(v[i]);
        float hf = __uint_as_float(h[i] << 16);
        l[i] = bf16_rne(v[i] - hf);
    }
    // fragment-ordered offset
    int tile = (row >> 7) * 16 + (k0 >> 5);
    int rp = row & 127, kp = k0 & 31;
    int c  = (rp >> 5) * 2 + (kp >> 4);
    int L  = (rp & 31) + (((kp >> 3) & 1) << 5);
    size_t off = (size_t)tile * 4096 + c * 512 + L * 8;   // ushort units
    uint4 ph, pl;
    ph.x = h[0] | (h[1] << 16); ph.y = h[2] | (h[3] << 16);
    ph.z = h[4] | (h[5] << 16); ph.w = h[6] | (h[7] << 16);
    pl.x = l[0] | (l[1] << 16); pl.y = l[2] | (l[3] << 16);
    pl.z = l[4] | (l[5] << 16); pl.w = l[6] | (l[7] << 16);
    if (isA) {
        *(uint4*)(ahi + off) = ph;
        *(uint4*)(alo + off) = pl;
    } else {
        *(uint4*)(bhi + off) = ph;
        *(uint4*)(blo + off) = pl;
        #pragma unroll
        for (int o = 32; o > 0; o >>= 1) s += __shfl_down(s, o);
        if (lane == 0) enorm[row] = s;
    }
}

// ===========================================================================
// Kernel 2: MFMA distance-GEMM + fused per-row argmin.
// grid 512, block 256 (4 waves, wave tile 64x64 = 2x2 of 32x32x16).
// NO LDS / NO barriers in the main loop: within a 128x128 block each A/B byte
// is consumed by exactly one wave, so fragments are loaded straight from
// global (fragment-ordered => coalesced) into VGPRs, software-pipelined at
// k16-phase granularity (prefetch p+2 while computing p, 8 loads + 12 MFMA
// per phase).
// XCD swizzle: XCD j = q%8 hosts bx in [8j,8j+8) -> 2 MB A stays L2-resident.
__global__ __launch_bounds__(256, 2) void vq_mfma_kernel(
        const ushort_t* __restrict__ ahi, const ushort_t* __restrict__ alo,
        const ushort_t* __restrict__ bhi, const ushort_t* __restrict__ blo,
        const float* __restrict__ enorm,
        float* __restrict__ pmin, int* __restrict__ pidx) {
    __shared__ __align__(16) ushort_t smem[32768];   // reduction only (64 KB)

    const int tid  = threadIdx.x;
    const int wave = tid >> 6, lane = tid & 63;
    const int l31  = lane & 31, half = lane >> 5;
    const int q  = blockIdx.x;
    const int bx = (q & 7) * 8 + (q >> 6);    // 0..63 row block; XCD = q%8
    const int by = (q >> 3) & 7;              // 0..7 col slice (1024 cols)
    const int wrow = (wave >> 1) * 64;
    const int wcol = (wave & 1) * 64;
    // lane-invariant part of a fragment address (ushort units)
    const int aoff = (wrow >> 6) * 2048 + lane * 8;
    const int boff = (wcol >> 6) * 2048 + lane * 8;

    f32x16 acc[2][2];
    #pragma unroll
    for (int i = 0; i < 2; ++i)
        #pragma unroll
        for (int j = 0; j < 2; ++j)
            #pragma unroll
            for (int r = 0; r < 16; ++r) acc[i][j][r] = 0.0f;

    float bestd[32];
    int   besti[32];
    #pragma unroll
    for (int i = 0; i < 32; ++i) { bestd[i] = 3.4e38f; besti[i] = 0x7FFFFFFF; }

    // phase p = n*2 + k16, p in [0,256). Buffer: [0..1]=ah(ti), [2..3]=al,
    // [4..5]=bh(tj), [6..7]=bl. Chunk for (ti,k16) is ti*2+k16.
    auto loadPhase = [&](int p, short8* P) {
        const int n = p >> 1, k16 = p & 1;
        const size_t abase = (size_t)(bx * 16 + (n & 15)) * 4096;
        const size_t bbase = (size_t)(by * 128 + n) * 4096;
        const ushort_t* pa = ahi + abase + aoff;
        const ushort_t* qa = alo + abase + aoff;
        const ushort_t* pb = bhi + bbase + boff;
        const ushort_t* qb = blo + bbase + boff;
        P[0] = *(const short8*)(pa + (k16) * 512);
        P[1] = *(const short8*)(pa + (2 + k16) * 512);
        P[2] = *(const short8*)(qa + (k16) * 512);
        P[3] = *(const short8*)(qa + (2 + k16) * 512);
        P[4] = *(const short8*)(pb + (k16) * 512);
        P[5] = *(const short8*)(pb + (2 + k16) * 512);
        P[6] = *(const short8*)(qb + (k16) * 512);
        P[7] = *(const short8*)(qb + (2 + k16) * 512);
    };

    auto computePhase = [&](const short8* P) {
        #pragma unroll
        for (int ti = 0; ti < 2; ++ti)
            #pragma unroll
            for (int tj = 0; tj < 2; ++tj) {
                acc[ti][tj] = __builtin_amdgcn_mfma_f32_32x32x16_bf16(
                    P[ti], P[4 + tj], acc[ti][tj], 0, 0, 0);
                acc[ti][tj] = __builtin_amdgcn_mfma_f32_32x32x16_bf16(
                    P[ti], P[6 + tj], acc[ti][tj], 0, 0, 0);
                acc[ti][tj] = __builtin_amdgcn_mfma_f32_32x32x16_bf16(
                    P[2 + ti], P[4 + tj], acc[ti][tj], 0, 0, 0);
            }
    };

    short8 P0[8], P1[8];
    loadPhase(0, P0);
    loadPhase(1, P1);

    for (int p = 0; p < 256; p += 2) {
        computePhase(P0);
        if (p + 2 < 256) loadPhase(p + 2, P0);
        computePhase(P1);
        if (p + 3 < 256) loadPhase(p + 3, P1);

        if ((p & 31) == 30) {
            // epilogue for col tile ct: dist' = ||e||^2 - 2*dot (xn drops out)
            const int ct = p >> 5;
            const int colbase = by * 1024 + ct * 128 + wcol;
            #pragma unroll
            for (int tj = 0; tj < 2; ++tj) {
                const int ci = colbase + tj * 32 + l31;
                const float en = enorm[ci];
                #pragma unroll
                for (int ti = 0; ti < 2; ++ti)
                    #pragma unroll
                    for (int reg = 0; reg < 16; ++reg) {
                        float d = en - 2.0f * acc[ti][tj][reg];
                        int s = ti * 16 + reg;
                        if (d < bestd[s]) { bestd[s] = d; besti[s] = ci; }
                    }
            }
            #pragma unroll
            for (int i = 0; i < 2; ++i)
                #pragma unroll
                for (int j = 0; j < 2; ++j)
                    #pragma unroll
                    for (int r = 0; r < 16; ++r) acc[i][j][r] = 0.0f;
        }
    }

    // ---- block argmin reduction: 64 candidates per row ----
    // slot-major [slot][128 rows]: conflict-free reads in the scan phase
    float* rd = (float*)smem;           // 64*128 floats = 32 KB
    int*   ri = (int*)smem + 8192;      // 64*128 ints   = 32 KB
    __syncthreads();
    const int slot = (wave & 1) * 32 + l31;
    #pragma unroll
    for (int ti = 0; ti < 2; ++ti)
        #pragma unroll
        for (int reg = 0; reg < 16; ++reg) {
            int row = wrow + ti * 32 + (reg & 3) + 8 * (reg >> 2) + 4 * half;
            rd[slot * 128 + row] = bestd[ti * 16 + reg];
            ri[slot * 128 + row] = besti[ti * 16 + reg];
        }
    __syncthreads();
    if (tid < 128) {
        float bd = rd[tid];
        int   bi = ri[tid];
        #pragma unroll 8
        for (int t = 1; t < 64; ++t) {
            float d = rd[t * 128 + tid];
            int  ii = ri[t * 128 + tid];
            if (d < bd || (d == bd && ii < bi)) { bd = d; bi = ii; }
        }
        pmin[(size_t)(bx * 128 + tid) * 8 + by] = bd;
        pidx[(size_t)(bx * 128 + tid) * 8 + by] = bi;
    }
}

// ===========================================================================
// Kernel 3: combine slice partials -> idx, then gather codebook row,
// exact fp32 ||x-e||^2 -> min_distances + loss partials. One 64-lane group/row.
__global__ __launch_bounds__(256) void finish_kernel(const float* __restrict__ x,
                                                     const float* __restrict__ cb,
                                                     const float* __restrict__ pmin,
                                                     const int* __restrict__ pidx,
                                                     float* __restrict__ out_idx,
                                                     float* __restrict__ qout,
                                                     float* __restrict__ out_mind,
                                                     float* __restrict__ lpart) {
    __shared__ float sred[4];
    int row  = blockIdx.x * 4 + (threadIdx.x >> 6);
    int lane = threadIdx.x & 63;

    // per-row argmin over the 8 slice partials (lanes 0..7 active)
    float d = (lane < 8) ? pmin[(size_t)row * 8 + lane] : 3.4e38f;
    int  ii = (lane < 8) ? pidx[(size_t)row * 8 + lane] : 0x7FFFFFFF;
    #pragma unroll
    for (int o = 4; o > 0; o >>= 1) {
        float d2 = __shfl_down(d, o);
        int   i2 = __shfl_down(ii, o);
        if (d2 < d || (d2 == d && i2 < ii)) { d = d2; ii = i2; }
    }
    int idx = __shfl(ii, 0);
    if (lane == 0) out_idx[row] = (float)idx;

    const float4* e4 = (const float4*)(cb + (size_t)idx * DIM);
    const float4* x4 = (const float4*)(x + (size_t)row * DIM);
    float4* q4 = (float4*)(qout + (size_t)row * DIM);
    float s = 0.0f;
    #pragma unroll
    for (int u = 0; u < 2; ++u) {
        float4 e  = e4[lane + u * 64];
        float4 xv = x4[lane + u * 64];
        q4[lane + u * 64] = e;
        float dx = xv.x - e.x, dy = xv.y - e.y, dz = xv.z - e.z, dw = xv.w - e.w;
        s += dx * dx + dy * dy + dz * dz + dw * dw;
    }
    #pragma unroll
    for (int o = 32; o > 0; o >>= 1) s += __shfl_down(s, o);
    if (lane == 0) { sred[threadIdx.x >> 6] = s; out_mind[row] = s; }
    __syncthreads();
    if (threadIdx.x == 0) lpart[blockIdx.x] = sred[0] + sred[1] + sred[2] + sred[3];
}

// ===========================================================================
// Kernel 4: final loss. loss_vq == loss_commit numerically => loss = 1.25*commit
__global__ __launch_bounds__(256) void loss_kernel(const float* __restrict__ lpart,
                                                   float* __restrict__ out_loss,
                                                   float* __restrict__ out_commit) {
    __shared__ float sm[256];
    float s = 0.0f;
    for (int i = threadIdx.x; i < 2048; i += 256) s += lpart[i];
    sm[threadIdx.x] = s;
    __syncthreads();
    #pragma unroll
    for (int o = 128; o > 0; o >>= 1) {
        if (threadIdx.x < o) sm[threadIdx.x] += sm[threadIdx.x + o];
        __syncthreads();
    }
    if (threadIdx.x == 0) {
        *out_commit = sm[0];
        *out_loss   = 1.25f * sm[0];
    }
}

// ===========================================================================
extern "C" void kernel_launch(void* const* d_in, const int* in_sizes, int n_in,
                              void* d_out, int out_size, void* d_ws, size_t ws_size,
                              hipStream_t stream) {
    const float* x  = (const float*)d_in[0];
    const float* cb = (const float*)d_in[1];
    float* out = (float*)d_out;
    float* ws  = (float*)d_ws;

    // A hi/lo staged in the quantized-output region (rewritten by finish_kernel)
    ushort_t* ahi = (ushort_t*)d_out;
    ushort_t* alo = (ushort_t*)d_out + 4194304;
    ushort_t* bhi = (ushort_t*)(ws + WS_BHI);
    ushort_t* blo = (ushort_t*)(ws + WS_BLO);
    float* enorm = ws + WS_ENORM;
    float* pmin  = ws + WS_PMIN;
    int*   pidx  = (int*)(ws + WS_PIDX);
    float* lpart = ws + WS_LPART;

    conv_kernel<<<4096, 256, 0, stream>>>(x, cb, ahi, alo, bhi, blo, enorm);
    vq_mfma_kernel<<<512, 256, 0, stream>>>(ahi, alo, bhi, blo, enorm, pmin, pidx);
    finish_kernel<<<NROWS / 4, 256, 0, stream>>>(x, cb, pmin, pidx,
                                                 out + OUT_IDX, out + OUT_Q,
                                                 out + OUT_MIND, lpart);
    loss_kernel<<<1, 256, 0, stream>>>(lpart, out + OUT_LOSS, out + OUT_COMMIT);
}